// Round 6
// baseline (686.710 us; speedup 1.0000x reference)
//
#include <hip/hip_runtime.h>
#include <math.h>

#define HIDDEN 768
#define HEADS 12
#define HD 64
#define SEQ 2048
#define BATCH 2
#define KK 204
#define QB 16
#define NTH 1024

typedef __attribute__((ext_vector_type(8))) short short8;
typedef __attribute__((ext_vector_type(4))) float f32x4;

// monotonic float->uint key (larger float => larger key)
__device__ __forceinline__ unsigned fkey(float f) {
    unsigned u = __float_as_uint(f);
    return u ^ ((unsigned)((int)u >> 31) | 0x80000000u);
}
__device__ __forceinline__ float fival(unsigned k) {
    unsigned u = k ^ ((k & 0x80000000u) ? 0x80000000u : 0xFFFFFFFFu);
    return __uint_as_float(u);
}
__device__ __forceinline__ unsigned short bf16h(float f) {
    unsigned u = __float_as_uint(f);
    return (unsigned short)((u + 0x7FFFu + ((u >> 16) & 1u)) >> 16);
}
__device__ __forceinline__ float bf16f(unsigned short h) {
    return __uint_as_float(((unsigned)h) << 16);
}

// swizzled fp32 score LDS index (float4-group XOR row&7) — row stride 2048 f32
#define SIDX(r,k) (((r)<<11) + (((((k)>>2) ^ ((r)&7))) << 2) + ((k)&3))

// ---------------------------------------------------------------------------
// Convert fp32 row-major [rows x 768] into MFMA fragment layout bf16 hi/lo.
// ---------------------------------------------------------------------------
__global__ __launch_bounds__(256)
void cvt_frag(const float* __restrict__ in, unsigned short* __restrict__ oh,
              unsigned short* __restrict__ ol, int rows)
{
    const int t = blockIdx.x * 256 + threadIdx.x;
    if (t >= rows * 96) return;
    const int lane = t & 63;
    const int kc   = (t >> 6) % 24;
    const int rblk = t / (24 * 64);
    const int r = rblk * 16 + (lane & 15);
    const int k = kc * 32 + (lane >> 4) * 8;
    const float4 a = *(const float4*)&in[(size_t)r * 768 + k];
    const float4 b = *(const float4*)&in[(size_t)r * 768 + k + 4];
    const float v[8] = {a.x, a.y, a.z, a.w, b.x, b.y, b.z, b.w};
    short8 sh, sl;
    #pragma unroll
    for (int j = 0; j < 8; ++j) {
        const unsigned short hh = bf16h(v[j]);
        sh[j] = (short)hh;
        sl[j] = (short)bf16h(v[j] - bf16f(hh));
    }
    *(short8*)&oh[(size_t)t * 8] = sh;
    *(short8*)&ol[(size_t)t * 8] = sl;
}

// ---------------------------------------------------------------------------
// Projection GEMM via split-bf16 MFMA: y = x @ W^T + b, M=4096, N=K=768.
// MODE 0: bf16 hi/lo in attn Q/K fragment layout
// MODE 1: bf16 hi/lo in attn V fragment layout
// ---------------------------------------------------------------------------
template<int MODE>
__global__ __launch_bounds__(256)
void proj_mfma(const unsigned short* __restrict__ Ah, const unsigned short* __restrict__ Al,
               const unsigned short* __restrict__ Bh, const unsigned short* __restrict__ Bl,
               const float* __restrict__ bias,
               unsigned short* __restrict__ Oh, unsigned short* __restrict__ Ol)
{
    const int w = threadIdx.x >> 6, lane = threadIdx.x & 63;
    const int n0 = blockIdx.x * 64;
    const int m0 = blockIdx.y * 64 + w * 16;
    const int mblk = m0 >> 4;
    f32x4 acc[4] = {};
    for (int kc = 0; kc < 24; ++kc) {
        const short8 ah = *(const short8*)&Ah[((size_t)(mblk * 24 + kc) * 64 + lane) * 8];
        const short8 al = *(const short8*)&Al[((size_t)(mblk * 24 + kc) * 64 + lane) * 8];
        #pragma unroll
        for (int nt = 0; nt < 4; ++nt) {
            const int nblk = (n0 >> 4) + nt;
            const short8 bh8 = *(const short8*)&Bh[((size_t)(nblk * 24 + kc) * 64 + lane) * 8];
            const short8 bl8 = *(const short8*)&Bl[((size_t)(nblk * 24 + kc) * 64 + lane) * 8];
            acc[nt] = __builtin_amdgcn_mfma_f32_16x16x32_bf16(ah, bh8, acc[nt], 0, 0, 0);
            acc[nt] = __builtin_amdgcn_mfma_f32_16x16x32_bf16(ah, bl8, acc[nt], 0, 0, 0);
            acc[nt] = __builtin_amdgcn_mfma_f32_16x16x32_bf16(al, bh8, acc[nt], 0, 0, 0);
        }
    }
    const int col = lane & 15, rg = lane >> 4;
    #pragma unroll
    for (int nt = 0; nt < 4; ++nt) {
        const int n = n0 + nt * 16 + col;
        const int h = n >> 6, dh = n & 63;
        const float bb = bias[n];
        #pragma unroll
        for (int r = 0; r < 4; ++r) {
            const int m = m0 + rg * 4 + r;
            const int b = m >> 11, s = m & (SEQ - 1);
            const float v = acc[nt][r] + bb;
            const unsigned short vh = bf16h(v);
            if (MODE == 0) {
                const int t = s >> 4, colq = s & 15;
                const int ks = dh >> 5, kg = (dh >> 3) & 3, j = dh & 7;
                const size_t addr = ((((size_t)(b * HEADS + h) * 128 + t) * 2 + ks) * 64 + kg * 16 + colq) * 8 + j;
                Oh[addr] = vh;
                Ol[addr] = bf16h(v - bf16f(vh));
            } else {
                const int dt = dh >> 4, colv = dh & 15;
                const int kc2 = s >> 5, kg = (s >> 3) & 3, j = s & 7;
                const size_t addr = ((((size_t)(b * HEADS + h) * 4 + dt) * 64 + kc2) * 64 + kg * 16 + colv) * 8 + j;
                Oh[addr] = vh;
                Ol[addr] = bf16h(v - bf16f(vh));
            }
        }
    }
}

// ---------------------------------------------------------------------------
// Output GEMM: out = AO @ Wo^T + bo (fp32 out), AO/Wo in fragment layout.
// ---------------------------------------------------------------------------
__global__ __launch_bounds__(256)
void gemm_out(const unsigned short* __restrict__ Ah, const unsigned short* __restrict__ Al,
              const unsigned short* __restrict__ Bh, const unsigned short* __restrict__ Bl,
              const float* __restrict__ bias, float* __restrict__ out)
{
    const int w = threadIdx.x >> 6, lane = threadIdx.x & 63;
    const int n0 = blockIdx.x * 64;
    const int m0 = blockIdx.y * 64 + w * 16;
    const int mblk = m0 >> 4;
    f32x4 acc[4] = {};
    for (int kc = 0; kc < 24; ++kc) {
        const short8 ah = *(const short8*)&Ah[((size_t)(mblk * 24 + kc) * 64 + lane) * 8];
        const short8 al = *(const short8*)&Al[((size_t)(mblk * 24 + kc) * 64 + lane) * 8];
        #pragma unroll
        for (int nt = 0; nt < 4; ++nt) {
            const int nblk = (n0 >> 4) + nt;
            const short8 bh8 = *(const short8*)&Bh[((size_t)(nblk * 24 + kc) * 64 + lane) * 8];
            const short8 bl8 = *(const short8*)&Bl[((size_t)(nblk * 24 + kc) * 64 + lane) * 8];
            acc[nt] = __builtin_amdgcn_mfma_f32_16x16x32_bf16(ah, bh8, acc[nt], 0, 0, 0);
            acc[nt] = __builtin_amdgcn_mfma_f32_16x16x32_bf16(ah, bl8, acc[nt], 0, 0, 0);
            acc[nt] = __builtin_amdgcn_mfma_f32_16x16x32_bf16(al, bh8, acc[nt], 0, 0, 0);
        }
    }
    const int col = lane & 15, rg = lane >> 4;
    #pragma unroll
    for (int nt = 0; nt < 4; ++nt) {
        const int n = n0 + nt * 16 + col;
        const float bb = bias[n];
        #pragma unroll
        for (int r = 0; r < 4; ++r) {
            const int m = m0 + rg * 4 + r;
            out[(size_t)m * HIDDEN + n] = acc[nt][r] + bb;
        }
    }
}

// ---------------------------------------------------------------------------
// Fused sparse attention, low-sync edition. 1024 thr / (16 q-rows, h, b).
// Row state (hist, scores stripe, P stripe) is WAVE-PRIVATE (row == wave) —
// only 3 barriers: post-scores, pre-PV, PV-reduce. Radix passes 2-4 iterate
// a register candidate mask. P stored single-bf16 (stride 4096/row, own
// stripe only); V is split hi/lo for accuracy.
// ---------------------------------------------------------------------------
__global__ __launch_bounds__(NTH, 4)
void sparse_attn(const unsigned short* __restrict__ Qfh, const unsigned short* __restrict__ Qfl,
                 const unsigned short* __restrict__ Kfh, const unsigned short* __restrict__ Kfl,
                 const unsigned short* __restrict__ Vfh, const unsigned short* __restrict__ Vfl,
                 unsigned short* __restrict__ AOh, unsigned short* __restrict__ AOl)
{
    extern __shared__ float smem[];
    float*    scores = smem;                           // [16][2048] f32 (8KB stripes)
    unsigned* hist   = (unsigned*)(smem + QB * SEQ);   // [16][256]; later PV partial-C
    unsigned* state  = hist + QB * 256;                // [16][8] (only [5]=inv used cross-wave)

    const int tid = threadIdx.x;
    const int wv = tid >> 6, lane = tid & 63;
    const int qb = blockIdx.x;
    const int q0 = qb * QB;
    const int h = blockIdx.y, b = blockIdx.z;
    const int bh = b * HEADS + h;

    // ---- Phase A: scores = Q K^T / 8 (6 MFMA per 16x16 tile), 8 tiles/wave
    {
        const size_t qbase = ((size_t)bh * 128 + qb) * 1024;
        const short8 qh0 = *(const short8*)&Qfh[qbase + lane * 8];
        const short8 qh1 = *(const short8*)&Qfh[qbase + 512 + lane * 8];
        const short8 ql0 = *(const short8*)&Qfl[qbase + lane * 8];
        const short8 ql1 = *(const short8*)&Qfl[qbase + 512 + lane * 8];
        const int col = lane & 15, rg = lane >> 4;
        for (int i = 0; i < 8; ++i) {
            const int t = wv * 8 + i;
            const size_t kb = ((size_t)bh * 128 + t) * 1024 + lane * 8;
            const short8 kh0 = *(const short8*)&Kfh[kb];
            const short8 kh1 = *(const short8*)&Kfh[kb + 512];
            const short8 kl0 = *(const short8*)&Kfl[kb];
            const short8 kl1 = *(const short8*)&Kfl[kb + 512];
            f32x4 c = {};
            c = __builtin_amdgcn_mfma_f32_16x16x32_bf16(qh0, kh0, c, 0, 0, 0);
            c = __builtin_amdgcn_mfma_f32_16x16x32_bf16(qh1, kh1, c, 0, 0, 0);
            c = __builtin_amdgcn_mfma_f32_16x16x32_bf16(qh0, kl0, c, 0, 0, 0);
            c = __builtin_amdgcn_mfma_f32_16x16x32_bf16(qh1, kl1, c, 0, 0, 0);
            c = __builtin_amdgcn_mfma_f32_16x16x32_bf16(ql0, kh0, c, 0, 0, 0);
            c = __builtin_amdgcn_mfma_f32_16x16x32_bf16(ql1, kh1, c, 0, 0, 0);
            const int k = t * 16 + col;
            #pragma unroll
            for (int r = 0; r < 4; ++r) {
                const int row = rg * 4 + r;
                scores[SIDX(row, k)] = c[r] * 0.125f;
            }
        }
    }
    __syncthreads();     // barrier 1: cross-wave score transpose complete

    // ---- Select phase: row = wave (all row state wave-private, no barriers)
    const int row = wv, rt = lane;
    unsigned* st = state + row * 8;
    const int cx = row & 7;

    unsigned key[32];
    {
        const float4* srow4 = (const float4*)(scores + (row << 11));
        #pragma unroll
        for (int j = 0; j < 8; ++j) {
            const float4 v = srow4[rt + 64 * j];
            key[4*j+0] = fkey(v.x); key[4*j+1] = fkey(v.y);
            key[4*j+2] = fkey(v.z); key[4*j+3] = fkey(v.w);
        }
    }
    unsigned mk = 0;
    #pragma unroll
    for (int e = 0; e < 32; ++e) mk = max(mk, key[e]);
    #pragma unroll
    for (int d = 32; d >= 1; d >>= 1)
        mk = max(mk, (unsigned)__shfl_xor((int)mk, d, 64));
    const float mrow = fival(mk);

    // ---- exact top-KK threshold: pass 1 full histogram, passes 2-4 masked
    unsigned cmask = 0u;
    unsigned prefix = 0, rem = KK;
    for (int p = 0; p < 4; ++p) {
        const int shift = 24 - (p << 3);
        #pragma unroll
        for (int z = 0; z < 4; ++z) hist[row * 256 + rt + 64 * z] = 0;
        if (p == 0) {
            #pragma unroll
            for (int e = 0; e < 32; ++e)
                atomicAdd(&hist[row * 256 + (key[e] >> 24)], 1u);
        } else {
            unsigned m = cmask;
            while (m) {
                const int e = __builtin_ctz(m); m &= m - 1u;
                atomicAdd(&hist[row * 256 + ((key[e] >> shift) & 255u)], 1u);
            }
        }
        // descending scan: lane rt owns bins [255-4rt .. 252-4rt]
        unsigned hloc[4]; unsigned s_local = 0;
        #pragma unroll
        for (int e2 = 0; e2 < 4; ++e2) { hloc[e2] = hist[row * 256 + 255 - 4 * rt - e2]; s_local += hloc[e2]; }
        unsigned inc = s_local;
        #pragma unroll
        for (int d = 1; d < 64; d <<= 1) {
            const unsigned o = (unsigned)__shfl_up((int)inc, (unsigned)d, 64);
            if (rt >= d) inc += o;
        }
        const unsigned s_above = inc - s_local;
        unsigned fval = 0xFFFFFFFFu;
        if (s_above < rem && s_above + s_local >= rem) {
            unsigned cum = s_above;
            #pragma unroll
            for (int e2 = 0; e2 < 4; ++e2) {
                const unsigned c2 = hloc[e2];
                if (cum + c2 >= rem) { fval = ((unsigned)(255 - 4 * rt - e2) << 16) | (rem - cum); break; }
                cum += c2;
            }
        }
        const unsigned long long bb = __ballot(fval != 0xFFFFFFFFu);
        const int src = __ffsll((unsigned long long)bb) - 1;
        fval = (unsigned)__shfl((int)fval, src, 64);
        const unsigned seld = fval >> 16;
        rem = fval & 0xFFFFu;
        prefix |= seld << shift;
        // refine candidate mask
        if (p == 0) {
            unsigned nm = 0;
            #pragma unroll
            for (int e = 0; e < 32; ++e)
                if ((key[e] >> 24) == seld) nm |= 1u << e;
            cmask = nm;
        } else {
            unsigned nm = 0, m = cmask;
            if (p < 3) {
                while (m) { const int e = __builtin_ctz(m); m &= m - 1u;
                    if (((key[e] >> shift) & 255u) == seld) nm |= 1u << e; }
            } else {
                while (m) { const int e = __builtin_ctz(m); m &= m - 1u;
                    if (key[e] == prefix) nm |= 1u << e; }
            }
            cmask = nm;
        }
    }
    const unsigned t = prefix;       // key of the KK-th largest
    const unsigned rem_eq = rem;     // how many ==t to include

    // ---- tie handling (lowest-index-first); rare
    int icut = SEQ;
    {
        unsigned cE = __popc(cmask);
        #pragma unroll
        for (int d = 32; d >= 1; d >>= 1) cE += (unsigned)__shfl_xor((int)cE, d, 64);
        if (rt == 0 && cE > rem_eq) {
            unsigned c2 = 0;
            for (int k = 0; k < SEQ; ++k)
                if (fkey(scores[SIDX(row, k)]) == t) { if (++c2 == rem_eq) { icut = k; break; } }
        }
        icut = __shfl(icut, 0, 64);
    }

    // ---- P = exp(s - m) on selected, 0 elsewhere; single-bf16, OWN stripe
    unsigned short* PH = (unsigned short*)smem;      // stride 4096 ushorts/row
    {
        float psum = 0.f;
        #pragma unroll
        for (int j = 0; j < 8; ++j) {
            const int G = rt + 64 * j;
            const int gx = G ^ cx;
            unsigned short ph[4];
            #pragma unroll
            for (int e = 0; e < 4; ++e) {
                const unsigned u = key[4*j+e];
                const int k = 4 * gx + e;
                float pv = 0.f;
                if (u > t || (u == t && k <= icut)) pv = __expf(fival(u) - mrow);
                const unsigned short hh = bf16h(pv);
                ph[e] = hh;
                psum += bf16f(hh);
            }
            const int g16 = (gx >> 1) ^ cx;
            const int off = (row << 12) + (g16 << 3) + ((gx & 1) << 2);
            uint2 wph; wph.x = (unsigned)ph[0] | ((unsigned)ph[1] << 16);
            wph.y = (unsigned)ph[2] | ((unsigned)ph[3] << 16);
            *(uint2*)&PH[off] = wph;
        }
        #pragma unroll
        for (int d = 32; d >= 1; d >>= 1) psum += __shfl_xor(psum, d, 64);
        if (rt == 0) st[5] = __float_as_uint(1.0f / psum);
    }
    __syncthreads();     // barrier 2: all P stripes + denominators ready

    // ---- PV via MFMA: wave = (kv-slice kq, dh-tile dt); P x (Vh+Vl)
    {
        const int dt = wv & 3, kq = wv >> 2;
        const int coll = lane & 15, kg = lane >> 4;
        const int c8 = coll & 7;
        f32x4 acc = {};
        for (int kc = 0; kc < 16; ++kc) {
            const int kv0 = kq * 512 + kc * 32 + kg * 8;
            const int aoff = (coll << 12) + (((kv0 >> 3) ^ c8) << 3);
            const short8 pa = *(const short8*)&PH[aoff];
            const size_t vidx = (((size_t)bh * 4 + dt) * 64 + kq * 16 + kc) * 512 + lane * 8;
            const short8 vh = *(const short8*)&Vfh[vidx];
            const short8 vl = *(const short8*)&Vfl[vidx];
            acc = __builtin_amdgcn_mfma_f32_16x16x32_bf16(pa, vh, acc, 0, 0, 0);
            acc = __builtin_amdgcn_mfma_f32_16x16x32_bf16(pa, vl, acc, 0, 0, 0);
        }
        float* red = (float*)hist;
        if (kq > 0) *(f32x4*)&red[(((kq - 1) * 4 + dt) * 64 + lane) << 2] = acc;
        __syncthreads();     // barrier 3: PV partials
        if (kq == 0) {
            #pragma unroll
            for (int q2 = 0; q2 < 3; ++q2) {
                const f32x4 o = *(const f32x4*)&red[((q2 * 4 + dt) * 64 + lane) << 2];
                acc[0] += o[0]; acc[1] += o[1]; acc[2] += o[2]; acc[3] += o[3];
            }
            #pragma unroll
            for (int r = 0; r < 4; ++r) {
                const int rw = (lane >> 4) * 4 + r;
                const float inv = __uint_as_float(state[rw * 8 + 5]);
                const float v = acc[r] * inv;
                const int n = h * 64 + dt * 16 + coll;
                const int m = b * SEQ + q0 + rw;
                const int mblk = m >> 4, mrow2 = m & 15;
                const int ks = n >> 5, kg2 = (n >> 3) & 3, j2 = n & 7;
                const size_t a2 = (((size_t)mblk * 24 + ks) * 64 + kg2 * 16 + mrow2) * 8 + j2;
                const unsigned short vh2 = bf16h(v);
                AOh[a2] = vh2;
                AOl[a2] = bf16h(v - bf16f(vh2));
            }
        }
    }
}

// ---------------------------------------------------------------------------
extern "C" void kernel_launch(void* const* d_in, const int* in_sizes, int n_in,
                              void* d_out, int out_size, void* d_ws, size_t ws_size,
                              hipStream_t stream)
{
    const float* x  = (const float*)d_in[0];
    const float* Wq = (const float*)d_in[1];
    const float* bq = (const float*)d_in[2];
    const float* Wk = (const float*)d_in[3];
    const float* bk = (const float*)d_in[4];
    const float* Wv = (const float*)d_in[5];
    const float* bv = (const float*)d_in[6];
    const float* Wo = (const float*)d_in[7];
    const float* bo = (const float*)d_in[8];

    unsigned short* U = (unsigned short*)d_ws;
    const size_t SZ = (size_t)BATCH * SEQ * HIDDEN;   // 3,145,728
    const size_t WSZ = (size_t)HIDDEN * HIDDEN;       //   589,824
    unsigned short* xh  = U;                // later reused as AOh
    unsigned short* xl  = U + SZ;           // later reused as AOl
    unsigned short* Qh  = U + 2 * SZ;
    unsigned short* Ql  = U + 3 * SZ;
    unsigned short* Kh  = U + 4 * SZ;
    unsigned short* Kl  = U + 5 * SZ;
    unsigned short* Vth = U + 6 * SZ;
    unsigned short* Vtl = U + 7 * SZ;
    unsigned short* wth = U + 8 * SZ;
    unsigned short* wtl = wth + WSZ;
    unsigned short* woh = wtl + WSZ;
    unsigned short* wol = woh + WSZ;

    const dim3 gg(HIDDEN / 64, (BATCH * SEQ) / 64);

    cvt_frag<<<1536, 256, 0, stream>>>(x, xh, xl, BATCH * SEQ);
    cvt_frag<<<288, 256, 0, stream>>>(Wo, woh, wol, HIDDEN);

    cvt_frag<<<288, 256, 0, stream>>>(Wq, wth, wtl, HIDDEN);
    proj_mfma<0><<<gg, 256, 0, stream>>>(xh, xl, wth, wtl, bq, Qh, Ql);
    cvt_frag<<<288, 256, 0, stream>>>(Wk, wth, wtl, HIDDEN);
    proj_mfma<0><<<gg, 256, 0, stream>>>(xh, xl, wth, wtl, bk, Kh, Kl);
    cvt_frag<<<288, 256, 0, stream>>>(Wv, wth, wtl, HIDDEN);
    proj_mfma<1><<<gg, 256, 0, stream>>>(xh, xl, wth, wtl, bv, Vth, Vtl);

    const int shbytes = (QB * SEQ + QB * 256 + QB * 8) * 4;   // 147,968 B
    hipFuncSetAttribute((const void*)sparse_attn,
                        hipFuncAttributeMaxDynamicSharedMemorySize, shbytes);
    sparse_attn<<<dim3(SEQ / QB, HEADS, BATCH), NTH, shbytes, stream>>>(
        Qh, Ql, Kh, Kl, Vth, Vtl, xh, xl);

    gemm_out<<<gg, 256, 0, stream>>>(xh, xl, woh, wol, bo, (float*)d_out);
}

// Round 7
// 526.345 us; speedup vs baseline: 1.3047x; 1.3047x over previous
//
#include <hip/hip_runtime.h>
#include <math.h>

#define HIDDEN 768
#define HEADS 12
#define HD 64
#define SEQ 2048
#define BATCH 2
#define KK 204
#define QB 16
#define NTH 1024

typedef __attribute__((ext_vector_type(8))) short short8;
typedef __attribute__((ext_vector_type(4))) float f32x4;

// monotonic float->uint key (larger float => larger key)
__device__ __forceinline__ unsigned fkey(float f) {
    unsigned u = __float_as_uint(f);
    return u ^ ((unsigned)((int)u >> 31) | 0x80000000u);
}
__device__ __forceinline__ float fival(unsigned k) {
    unsigned u = k ^ ((k & 0x80000000u) ? 0x80000000u : 0xFFFFFFFFu);
    return __uint_as_float(u);
}
__device__ __forceinline__ unsigned short bf16h(float f) {
    unsigned u = __float_as_uint(f);
    return (unsigned short)((u + 0x7FFFu + ((u >> 16) & 1u)) >> 16);
}
__device__ __forceinline__ float bf16f(unsigned short h) {
    return __uint_as_float(((unsigned)h) << 16);
}

// swizzled fp32 score LDS index (float4-group XOR row&7) — row stride 2048 f32
#define SIDX(r,k) (((r)<<11) + (((((k)>>2) ^ ((r)&7))) << 2) + ((k)&3))

// ---------------------------------------------------------------------------
// Convert fp32 row-major [rows x 768] into MFMA fragment layout bf16 hi/lo.
// ---------------------------------------------------------------------------
__global__ __launch_bounds__(256)
void cvt_frag(const float* __restrict__ in, unsigned short* __restrict__ oh,
              unsigned short* __restrict__ ol, int rows)
{
    const int t = blockIdx.x * 256 + threadIdx.x;
    if (t >= rows * 96) return;
    const int lane = t & 63;
    const int kc   = (t >> 6) % 24;
    const int rblk = t / (24 * 64);
    const int r = rblk * 16 + (lane & 15);
    const int k = kc * 32 + (lane >> 4) * 8;
    const float4 a = *(const float4*)&in[(size_t)r * 768 + k];
    const float4 b = *(const float4*)&in[(size_t)r * 768 + k + 4];
    const float v[8] = {a.x, a.y, a.z, a.w, b.x, b.y, b.z, b.w};
    short8 sh, sl;
    #pragma unroll
    for (int j = 0; j < 8; ++j) {
        const unsigned short hh = bf16h(v[j]);
        sh[j] = (short)hh;
        sl[j] = (short)bf16h(v[j] - bf16f(hh));
    }
    *(short8*)&oh[(size_t)t * 8] = sh;
    *(short8*)&ol[(size_t)t * 8] = sl;
}

// Batched weight conversion: blockIdx.y selects which of the 4 weights.
__global__ __launch_bounds__(256)
void cvt_frag_w(const float* __restrict__ W0, const float* __restrict__ W1,
                const float* __restrict__ W2, const float* __restrict__ W3,
                unsigned short* __restrict__ o0h, unsigned short* __restrict__ o0l,
                unsigned short* __restrict__ o1h, unsigned short* __restrict__ o1l,
                unsigned short* __restrict__ o2h, unsigned short* __restrict__ o2l,
                unsigned short* __restrict__ o3h, unsigned short* __restrict__ o3l)
{
    const float* in; unsigned short *oh, *ol;
    switch (blockIdx.y) {
        case 0:  in = W0; oh = o0h; ol = o0l; break;
        case 1:  in = W1; oh = o1h; ol = o1l; break;
        case 2:  in = W2; oh = o2h; ol = o2l; break;
        default: in = W3; oh = o3h; ol = o3l; break;
    }
    const int t = blockIdx.x * 256 + threadIdx.x;
    if (t >= 768 * 96) return;
    const int lane = t & 63;
    const int kc   = (t >> 6) % 24;
    const int rblk = t / (24 * 64);
    const int r = rblk * 16 + (lane & 15);
    const int k = kc * 32 + (lane >> 4) * 8;
    const float4 a = *(const float4*)&in[(size_t)r * 768 + k];
    const float4 b = *(const float4*)&in[(size_t)r * 768 + k + 4];
    const float v[8] = {a.x, a.y, a.z, a.w, b.x, b.y, b.z, b.w};
    short8 sh, sl;
    #pragma unroll
    for (int j = 0; j < 8; ++j) {
        const unsigned short hh = bf16h(v[j]);
        sh[j] = (short)hh;
        sl[j] = (short)bf16h(v[j] - bf16f(hh));
    }
    *(short8*)&oh[(size_t)t * 8] = sh;
    *(short8*)&ol[(size_t)t * 8] = sl;
}

// ---------------------------------------------------------------------------
// Fused Q/K/V projection via split-bf16 MFMA: blockIdx.z selects weight set.
// z=0: Q (attn Q/K fragment layout, hi/lo), z=1: K (same layout, hi/lo),
// z=2: V (attn V fragment layout, hi only).
// ---------------------------------------------------------------------------
__global__ __launch_bounds__(256)
void proj_fused(const unsigned short* __restrict__ Ah, const unsigned short* __restrict__ Al,
                const unsigned short* __restrict__ Wqh, const unsigned short* __restrict__ Wql,
                const unsigned short* __restrict__ Wkh, const unsigned short* __restrict__ Wkl,
                const unsigned short* __restrict__ Wvh, const unsigned short* __restrict__ Wvl,
                const float* __restrict__ bq, const float* __restrict__ bk,
                const float* __restrict__ bv,
                unsigned short* __restrict__ Qh, unsigned short* __restrict__ Ql,
                unsigned short* __restrict__ Kh, unsigned short* __restrict__ Kl,
                unsigned short* __restrict__ Vt)
{
    const unsigned short *Bh, *Bl; const float* bias;
    unsigned short *Oh, *Ol; int mode;
    if (blockIdx.z == 0)      { Bh = Wqh; Bl = Wql; bias = bq; Oh = Qh; Ol = Ql; mode = 0; }
    else if (blockIdx.z == 1) { Bh = Wkh; Bl = Wkl; bias = bk; Oh = Kh; Ol = Kl; mode = 0; }
    else                      { Bh = Wvh; Bl = Wvl; bias = bv; Oh = Vt; Ol = 0;  mode = 1; }

    const int w = threadIdx.x >> 6, lane = threadIdx.x & 63;
    const int n0 = blockIdx.x * 64;
    const int m0 = blockIdx.y * 64 + w * 16;
    const int mblk = m0 >> 4;
    f32x4 acc[4] = {};
    for (int kc = 0; kc < 24; ++kc) {
        const short8 ah = *(const short8*)&Ah[((size_t)(mblk * 24 + kc) * 64 + lane) * 8];
        const short8 al = *(const short8*)&Al[((size_t)(mblk * 24 + kc) * 64 + lane) * 8];
        #pragma unroll
        for (int nt = 0; nt < 4; ++nt) {
            const int nblk = (n0 >> 4) + nt;
            const short8 bh8 = *(const short8*)&Bh[((size_t)(nblk * 24 + kc) * 64 + lane) * 8];
            const short8 bl8 = *(const short8*)&Bl[((size_t)(nblk * 24 + kc) * 64 + lane) * 8];
            acc[nt] = __builtin_amdgcn_mfma_f32_16x16x32_bf16(ah, bh8, acc[nt], 0, 0, 0);
            acc[nt] = __builtin_amdgcn_mfma_f32_16x16x32_bf16(ah, bl8, acc[nt], 0, 0, 0);
            acc[nt] = __builtin_amdgcn_mfma_f32_16x16x32_bf16(al, bh8, acc[nt], 0, 0, 0);
        }
    }
    const int col = lane & 15, rg = lane >> 4;
    #pragma unroll
    for (int nt = 0; nt < 4; ++nt) {
        const int n = n0 + nt * 16 + col;
        const int h = n >> 6, dh = n & 63;
        const float bb = bias[n];
        #pragma unroll
        for (int r = 0; r < 4; ++r) {
            const int m = m0 + rg * 4 + r;
            const int b = m >> 11, s = m & (SEQ - 1);
            const float v = acc[nt][r] + bb;
            const unsigned short vh = bf16h(v);
            if (mode == 0) {
                const int t = s >> 4, colq = s & 15;
                const int ks = dh >> 5, kg = (dh >> 3) & 3, j = dh & 7;
                const size_t addr = ((((size_t)(b * HEADS + h) * 128 + t) * 2 + ks) * 64 + kg * 16 + colq) * 8 + j;
                Oh[addr] = vh;
                Ol[addr] = bf16h(v - bf16f(vh));
            } else {
                const int dt = dh >> 4, colv = dh & 15;
                const int kc2 = s >> 5, kg = (s >> 3) & 3, j = s & 7;
                const size_t addr = ((((size_t)(b * HEADS + h) * 4 + dt) * 64 + kc2) * 64 + kg * 16 + colv) * 8 + j;
                Oh[addr] = vh;
            }
        }
    }
}

// ---------------------------------------------------------------------------
// Output GEMM: out = AO @ Wo^T + bo (fp32 out), AO/Wo in fragment layout.
// ---------------------------------------------------------------------------
__global__ __launch_bounds__(256)
void gemm_out(const unsigned short* __restrict__ Ah, const unsigned short* __restrict__ Al,
              const unsigned short* __restrict__ Bh, const unsigned short* __restrict__ Bl,
              const float* __restrict__ bias, float* __restrict__ out)
{
    const int w = threadIdx.x >> 6, lane = threadIdx.x & 63;
    const int n0 = blockIdx.x * 64;
    const int m0 = blockIdx.y * 64 + w * 16;
    const int mblk = m0 >> 4;
    f32x4 acc[4] = {};
    for (int kc = 0; kc < 24; ++kc) {
        const short8 ah = *(const short8*)&Ah[((size_t)(mblk * 24 + kc) * 64 + lane) * 8];
        const short8 al = *(const short8*)&Al[((size_t)(mblk * 24 + kc) * 64 + lane) * 8];
        #pragma unroll
        for (int nt = 0; nt < 4; ++nt) {
            const int nblk = (n0 >> 4) + nt;
            const short8 bh8 = *(const short8*)&Bh[((size_t)(nblk * 24 + kc) * 64 + lane) * 8];
            const short8 bl8 = *(const short8*)&Bl[((size_t)(nblk * 24 + kc) * 64 + lane) * 8];
            acc[nt] = __builtin_amdgcn_mfma_f32_16x16x32_bf16(ah, bh8, acc[nt], 0, 0, 0);
            acc[nt] = __builtin_amdgcn_mfma_f32_16x16x32_bf16(ah, bl8, acc[nt], 0, 0, 0);
            acc[nt] = __builtin_amdgcn_mfma_f32_16x16x32_bf16(al, bh8, acc[nt], 0, 0, 0);
        }
    }
    const int col = lane & 15, rg = lane >> 4;
    #pragma unroll
    for (int nt = 0; nt < 4; ++nt) {
        const int n = n0 + nt * 16 + col;
        const float bb = bias[n];
        #pragma unroll
        for (int r = 0; r < 4; ++r) {
            const int m = m0 + rg * 4 + r;
            out[(size_t)m * HIDDEN + n] = acc[nt][r] + bb;
        }
    }
}

// ---------------------------------------------------------------------------
// Fused sparse attention (round-5 structure, verbatim numerics) + XCD-aware
// work swizzle: each XCD gets 384 consecutive work items = 3 (b,h) heads
// -> K/V L2-resident per XCD.
// ---------------------------------------------------------------------------
__global__ __launch_bounds__(NTH, 4)
void sparse_attn(const unsigned short* __restrict__ Qfh, const unsigned short* __restrict__ Qfl,
                 const unsigned short* __restrict__ Kfh, const unsigned short* __restrict__ Kfl,
                 const unsigned short* __restrict__ Vf,
                 unsigned short* __restrict__ AOh, unsigned short* __restrict__ AOl)
{
    extern __shared__ float smem[];
    float*    scores = smem;                           // 16*2048 f32 swizzled; later Ph/Pl overlay
    unsigned* hist   = (unsigned*)(smem + QB * SEQ);   // 16*256 (radix) / PV partial-C (16KB)
    unsigned* state  = hist + QB * 256;                // 16*8

    // ---- XCD-aware work remap (3072 = 8 XCDs x 384 work items)
    const int f = blockIdx.x + 128 * (blockIdx.y + 12 * blockIdx.z);
    const int wk = (f & 7) * 384 + (f >> 3);
    const int qb = wk & 127;
    const int h  = (wk >> 7) % 12;
    const int b  = wk / 1536;
    const int q0 = qb * QB;
    const int bh = b * HEADS + h;

    const int tid = threadIdx.x;
    const int wv = tid >> 6, lane = tid & 63;

    if (lane == 0) {                 // one wave per row: init own row state
        unsigned* s0 = state + wv * 8;
        s0[1] = 0; s0[2] = KK; s0[4] = SEQ;
    }

    // ---- Phase A: scores = Q K^T / 8 (6 MFMA per 16x16 tile), 8 tiles/wave
    {
        const size_t qbase = ((size_t)bh * 128 + qb) * 1024;
        const short8 qh0 = *(const short8*)&Qfh[qbase + lane * 8];
        const short8 qh1 = *(const short8*)&Qfh[qbase + 512 + lane * 8];
        const short8 ql0 = *(const short8*)&Qfl[qbase + lane * 8];
        const short8 ql1 = *(const short8*)&Qfl[qbase + 512 + lane * 8];
        const int col = lane & 15, rg = lane >> 4;
        for (int i = 0; i < 8; ++i) {
            const int t = wv * 8 + i;
            const size_t kb = ((size_t)bh * 128 + t) * 1024 + lane * 8;
            const short8 kh0 = *(const short8*)&Kfh[kb];
            const short8 kh1 = *(const short8*)&Kfh[kb + 512];
            const short8 kl0 = *(const short8*)&Kfl[kb];
            const short8 kl1 = *(const short8*)&Kfl[kb + 512];
            f32x4 c = {};
            c = __builtin_amdgcn_mfma_f32_16x16x32_bf16(qh0, kh0, c, 0, 0, 0);
            c = __builtin_amdgcn_mfma_f32_16x16x32_bf16(qh1, kh1, c, 0, 0, 0);
            c = __builtin_amdgcn_mfma_f32_16x16x32_bf16(qh0, kl0, c, 0, 0, 0);
            c = __builtin_amdgcn_mfma_f32_16x16x32_bf16(qh1, kl1, c, 0, 0, 0);
            c = __builtin_amdgcn_mfma_f32_16x16x32_bf16(ql0, kh0, c, 0, 0, 0);
            c = __builtin_amdgcn_mfma_f32_16x16x32_bf16(ql1, kh1, c, 0, 0, 0);
            const int k = t * 16 + col;
            #pragma unroll
            for (int r = 0; r < 4; ++r) {
                const int row = rg * 4 + r;
                scores[SIDX(row, k)] = c[r] * 0.125f;
            }
        }
    }
    __syncthreads();

    // ---- Phase B: exact top-KK per row; row = wave, 32 keys/lane in VGPRs
    const int row = wv, rt = lane;
    unsigned* st = state + row * 8;
    const int cx = row & 7;
    unsigned key[32];
    {
        const float4* srow4 = (const float4*)(scores + (row << 11));
        #pragma unroll
        for (int j = 0; j < 8; ++j) {
            const float4 v = srow4[rt + 64 * j];
            key[4*j+0] = fkey(v.x); key[4*j+1] = fkey(v.y);
            key[4*j+2] = fkey(v.z); key[4*j+3] = fkey(v.w);
        }
    }
    unsigned mk = 0;
    #pragma unroll
    for (int e = 0; e < 32; ++e) mk = max(mk, key[e]);
    #pragma unroll
    for (int d = 32; d >= 1; d >>= 1)
        mk = max(mk, (unsigned)__shfl_xor((int)mk, d, 64));
    const float mrow = fival(mk);

    for (int p = 0; p < 4; ++p) {
        const int shift = 24 - (p << 3);
        const unsigned maskHi = (p == 0) ? 0u : (0xFFFFFFFFu << (shift + 8));
        const unsigned prefix = st[1];
        const unsigned rem    = st[2];
        #pragma unroll
        for (int j2 = 0; j2 < 4; ++j2) hist[row * 256 + rt + 64 * j2] = 0;
        __syncthreads();
        #pragma unroll
        for (int e = 0; e < 32; ++e) {
            const unsigned u = key[e];
            if ((u & maskHi) == prefix)
                atomicAdd(&hist[row * 256 + ((u >> shift) & 255u)], 1u);
        }
        __syncthreads();
        // descending scan: lane rt owns bins [255-4rt .. 252-4rt]
        unsigned hloc[4]; unsigned s_local = 0;
        #pragma unroll
        for (int e = 0; e < 4; ++e) { hloc[e] = hist[row * 256 + 255 - 4 * rt - e]; s_local += hloc[e]; }
        unsigned inc = s_local;
        #pragma unroll
        for (int d = 1; d < 64; d <<= 1) {
            const unsigned o = (unsigned)__shfl_up((int)inc, (unsigned)d, 64);
            if (rt >= d) inc += o;
        }
        const unsigned s_above = inc - s_local;
        if (s_above < rem && s_above + s_local >= rem) {
            unsigned cum = s_above;
            #pragma unroll
            for (int e = 0; e < 4; ++e) {
                const unsigned c2 = hloc[e];
                if (cum + c2 >= rem) {
                    st[1] = prefix | ((unsigned)(255 - 4 * rt - e) << shift);
                    st[2] = rem - cum;
                    break;
                }
                cum += c2;
            }
        }
        __syncthreads();
    }
    const unsigned t      = st[1];
    const unsigned rem_eq = st[2];

    {   // tie handling (lowest-index-first); rare
        unsigned cE = 0;
        #pragma unroll
        for (int e = 0; e < 32; ++e) cE += (key[e] == t) ? 1u : 0u;
        #pragma unroll
        for (int d = 32; d >= 1; d >>= 1) cE += (unsigned)__shfl_xor((int)cE, d, 64);
        if (rt == 0 && cE > rem_eq) {
            unsigned c2 = 0;
            for (int k = 0; k < SEQ; ++k)
                if (fkey(scores[SIDX(row, k)]) == t) { if (++c2 == rem_eq) { st[4] = (unsigned)k; break; } }
        }
    }
    __syncthreads();           // all tie-scans done; scores may now be overlaid
    const int icut = (int)st[4];

    // ---- P = exp(s - m) on selected, 0 elsewhere; bf16 hi/lo overlay + denom
    unsigned short* PH = (unsigned short*)smem;
    unsigned short* PL = PH + QB * SEQ;
    {
        float psum = 0.f;
        #pragma unroll
        for (int j = 0; j < 8; ++j) {
            const int G = rt + 64 * j;
            const int gx = G ^ cx;
            unsigned short ph[4], pl[4];
            #pragma unroll
            for (int e = 0; e < 4; ++e) {
                const unsigned u = key[4*j+e];
                const int k = 4 * gx + e;
                float pv = 0.f;
                if (u > t || (u == t && k <= icut)) { pv = __expf(fival(u) - mrow); psum += pv; }
                const unsigned short hh = bf16h(pv);
                ph[e] = hh;
                pl[e] = bf16h(pv - bf16f(hh));
            }
            const int g16 = (gx >> 1) ^ cx;
            const int off = (row << 11) + (g16 << 3) + ((gx & 1) << 2);
            uint2 wph; wph.x = (unsigned)ph[0] | ((unsigned)ph[1] << 16);
            wph.y = (unsigned)ph[2] | ((unsigned)ph[3] << 16);
            *(uint2*)&PH[off] = wph;
            uint2 wpl; wpl.x = (unsigned)pl[0] | ((unsigned)pl[1] << 16);
            wpl.y = (unsigned)pl[2] | ((unsigned)pl[3] << 16);
            *(uint2*)&PL[off] = wpl;
        }
        #pragma unroll
        for (int d = 32; d >= 1; d >>= 1) psum += __shfl_xor(psum, d, 64);
        if (rt == 0) st[5] = __float_as_uint(1.0f / psum);
    }
    __syncthreads();

    // ---- PV via MFMA: wave = (kv-slice kq, dh-tile dt); split P x bf16 V
    {
        const int dt = wv & 3, kq = wv >> 2;
        const int coll = lane & 15, kg = lane >> 4;
        const int c8 = coll & 7;
        f32x4 acc = {};
        for (int kc = 0; kc < 16; ++kc) {
            const int kv0 = kq * 512 + kc * 32 + kg * 8;
            const int aoff = (coll << 11) + (((kv0 >> 3) ^ c8) << 3);
            const short8 pa = *(const short8*)&PH[aoff];
            const short8 pb = *(const short8*)&PL[aoff];
            const int kc2 = kq * 16 + kc;
            const short8 bv = *(const short8*)&Vf[(((size_t)bh * 4 + dt) * 64 + kc2) * 512 + lane * 8];
            acc = __builtin_amdgcn_mfma_f32_16x16x32_bf16(pa, bv, acc, 0, 0, 0);
            acc = __builtin_amdgcn_mfma_f32_16x16x32_bf16(pb, bv, acc, 0, 0, 0);
        }
        float* red = (float*)hist;
        if (kq > 0) *(f32x4*)&red[(((kq - 1) * 4 + dt) * 64 + lane) << 2] = acc;
        __syncthreads();
        if (kq == 0) {
            #pragma unroll
            for (int q2 = 0; q2 < 3; ++q2) {
                const f32x4 o = *(const f32x4*)&red[((q2 * 4 + dt) * 64 + lane) << 2];
                acc[0] += o[0]; acc[1] += o[1]; acc[2] += o[2]; acc[3] += o[3];
            }
            #pragma unroll
            for (int r = 0; r < 4; ++r) {
                const int rw = (lane >> 4) * 4 + r;
                const float inv = __uint_as_float(state[rw * 8 + 5]);
                const float v = acc[r] * inv;
                const int n = h * 64 + dt * 16 + coll;
                const int m = b * SEQ + q0 + rw;
                const int mblk = m >> 4, mrow2 = m & 15;
                const int ks = n >> 5, kg2 = (n >> 3) & 3, j2 = n & 7;
                const size_t a2 = (((size_t)mblk * 24 + ks) * 64 + kg2 * 16 + mrow2) * 8 + j2;
                const unsigned short vh = bf16h(v);
                AOh[a2] = vh;
                AOl[a2] = bf16h(v - bf16f(vh));
            }
        }
    }
}

// ---------------------------------------------------------------------------
extern "C" void kernel_launch(void* const* d_in, const int* in_sizes, int n_in,
                              void* d_out, int out_size, void* d_ws, size_t ws_size,
                              hipStream_t stream)
{
    const float* x  = (const float*)d_in[0];
    const float* Wq = (const float*)d_in[1];
    const float* bq = (const float*)d_in[2];
    const float* Wk = (const float*)d_in[3];
    const float* bk = (const float*)d_in[4];
    const float* Wv = (const float*)d_in[5];
    const float* bv = (const float*)d_in[6];
    const float* Wo = (const float*)d_in[7];
    const float* bo = (const float*)d_in[8];

    unsigned short* U = (unsigned short*)d_ws;
    const size_t SZ = (size_t)BATCH * SEQ * HIDDEN;   // 3,145,728
    const size_t WSZ = (size_t)HIDDEN * HIDDEN;       //   589,824
    unsigned short* xh  = U;                // later reused as AOh
    unsigned short* xl  = U + SZ;           // later reused as AOl
    unsigned short* Qh  = U + 2 * SZ;
    unsigned short* Ql  = U + 3 * SZ;
    unsigned short* Kh  = U + 4 * SZ;
    unsigned short* Kl  = U + 5 * SZ;
    unsigned short* Vt  = U + 6 * SZ;
    unsigned short* wqh = U + 7 * SZ;
    unsigned short* wql = wqh + WSZ;
    unsigned short* wkh = wqh + 2 * WSZ;
    unsigned short* wkl = wqh + 3 * WSZ;
    unsigned short* wvh = wqh + 4 * WSZ;
    unsigned short* wvl = wqh + 5 * WSZ;
    unsigned short* woh = wqh + 6 * WSZ;
    unsigned short* wol = wqh + 7 * WSZ;

    const dim3 gg(HIDDEN / 64, (BATCH * SEQ) / 64);

    cvt_frag<<<1536, 256, 0, stream>>>(x, xh, xl, BATCH * SEQ);
    cvt_frag_w<<<dim3(288, 4), 256, 0, stream>>>(Wq, Wk, Wv, Wo,
        wqh, wql, wkh, wkl, wvh, wvl, woh, wol);

    proj_fused<<<dim3(HIDDEN / 64, (BATCH * SEQ) / 64, 3), 256, 0, stream>>>(
        xh, xl, wqh, wql, wkh, wkl, wvh, wvl, bq, bk, bv, Qh, Ql, Kh, Kl, Vt);

    const int shbytes = (QB * SEQ + QB * 256 + QB * 8) * 4;   // 147,968 B
    hipFuncSetAttribute((const void*)sparse_attn,
                        hipFuncAttributeMaxDynamicSharedMemorySize, shbytes);
    sparse_attn<<<dim3(SEQ / QB, HEADS, BATCH), NTH, shbytes, stream>>>(
        Qh, Ql, Kh, Kl, Vt, xh, xl);

    gemm_out<<<gg, 256, 0, stream>>>(xh, xl, woh, wol, bo, (float*)d_out);
}